// Round 11
// baseline (240.661 us; speedup 1.0000x reference)
//
#include <hip/hip_runtime.h>
#include <hip/hip_fp16.h>
#include <math.h>

#define HDIM 128
#define LN_EPS 1e-5f
#define NCOH 8   // cohorts = SOURCE-RANGE SLICES (R23): cohort u holds edges with
                 // src in [u*N/8,(u+1)*N/8) => all waves walk slices in the same
                 // order => instantaneous gather working set ~1-2 slices (0.8-1.6MB),
                 // L2-resident in EVERY XCD (was: random over 6.4MB, ~40MB refetch)
#define CAP 24   // per-(node,cohort) slot capacity; Poisson(2) => P(overflow) ~1e-12

typedef _Float16 half8 __attribute__((ext_vector_type(8)));
typedef float f32x4 __attribute__((ext_vector_type(4)));
typedef float f32x2 __attribute__((ext_vector_type(2)));

// Base = R18/R22 split form (228.2/230.5us measured; fused & feature-split
// variants all regressed). Single-pass padded CSR (slot-major planes); h' fp8
// e4m3; meta[v] = {8 count-bytes, dinv} one 16B broadcast; gemm 64-row 4-wave
// LDS-staged; agg 2 nodes/wave, 4B/lane, 16-deep. R23 changes ONLY the cohort
// function in build_kernel (blockIdx&7 -> src-slice) to convert the
// latency-bound gather's L2 misses into hits via synchronized slice traversal.

// ---------------- CSR build: one pass, 2 edges/thread, src-sliced cohorts ----------------

__global__ void build_kernel(const int* __restrict__ src, const int* __restrict__ dst,
                             int* __restrict__ counts8, int* __restrict__ csr8,
                             int E, int n) {
  int t = blockIdx.x * blockDim.x + threadIdx.x;
  int M8 = NCOH * n;
  float scale = (float)NCOH / (float)n;
  int e0 = t * 2;
  if (e0 + 1 < E) {
    int2 d = *(const int2*)&dst[e0];
    int2 s = *(const int2*)&src[e0];
    int xa = min((int)((float)s.x * scale), NCOH - 1);
    int slot0 = atomicAdd(&counts8[xa * n + d.x], 1);
    if (slot0 < CAP) csr8[slot0 * M8 + xa * n + d.x] = s.x;
    int xb = min((int)((float)s.y * scale), NCOH - 1);
    int slot1 = atomicAdd(&counts8[xb * n + d.y], 1);
    if (slot1 < CAP) csr8[slot1 * M8 + xb * n + d.y] = s.y;
  } else if (e0 < E) {
    int dd = dst[e0];
    int ss = src[e0];
    int xa = min((int)((float)ss * scale), NCOH - 1);
    int slot = atomicAdd(&counts8[xa * n + dd], 1);
    if (slot < CAP) csr8[slot * M8 + xa * n + dd] = ss;
  }
}

// ---------------- Prep: meta (packed counts+dinv), dinv, xs (fp16), fp16-T weights ----

__global__ void prep_kernel(const float* __restrict__ x, const int* __restrict__ counts8,
                            float* __restrict__ dinv, __half* __restrict__ xs,
                            uint4* __restrict__ meta,
                            const float* __restrict__ W2, const float* __restrict__ W3,
                            const float* __restrict__ rW1, __half* __restrict__ w2t,
                            __half* __restrict__ w3t, __half* __restrict__ rw1t, int n) {
  int idx = blockIdx.x * 256 + threadIdx.x;
  int nx = n * 8;
  if (idx < nx) {
    int vv = idx >> 3, j = idx & 7;  // 8 lanes per node (group-aligned within wave)
    int c = counts8[j * n + vv];
    int s = c;
    s += __shfl_xor(s, 1, 8);
    s += __shfl_xor(s, 2, 8);
    s += __shfl_xor(s, 4, 8);
    float dv = rsqrtf((float)(s + 1));  // +1 self-loop (raw counts incl. overflow)
    xs[idx] = __float2half((j < 6) ? x[vv * 6 + j] * dv : 0.f);
    // pack meta[vv] = {counts bytes 0..7 (clamped to CAP), dinv, 0}
    unsigned w = (unsigned)min(c, CAP) << ((j & 3) * 8);
    w |= __shfl_xor(w, 1, 8);
    w |= __shfl_xor(w, 2, 8);
    unsigned other = __shfl_xor(w, 4, 8);
    unsigned lo = (j < 4) ? w : other;
    unsigned hi = (j < 4) ? other : w;
    unsigned comp = (j == 0) ? lo : (j == 1) ? hi : (j == 2) ? __float_as_uint(dv) : 0u;
    if (j < 4) ((unsigned*)meta)[vv * 4 + j] = comp;  // coalesced 16B/group
    if (j == 7) dinv[vv] = dv;
    return;
  }
  int i = idx - nx;
  if (i < 16384) {
    int nn = i >> 7, k = i & 127;
    w2t[i] = __float2half(W2[k * 128 + nn]);
  } else if (i < 32768) {
    int j = i - 16384;
    int nn = j >> 7, k = j & 127;
    w3t[j] = __float2half(W3[k * 128 + nn]);
  } else if (i < 40960) {
    int j = i - 32768;
    int nn = j >> 7, k = j & 127;
    rw1t[j] = __float2half(rW1[k * 64 + nn]);
  }
}

__device__ __forceinline__ void unpack_L(uint4 mt, int* L) {
  L[0] = 0;
  unsigned lo = mt.x, hi = mt.y;
#pragma unroll
  for (int u = 0; u < 4; ++u) L[u + 1] = L[u] + (int)((lo >> (u * 8)) & 255u);
#pragma unroll
  for (int u = 4; u < 8; ++u) L[u + 1] = L[u] + (int)((hi >> ((u - 4) * 8)) & 255u);
}

// ---------------- Layer 1: one wave/node; lane-owned edges, 1x uint4 (fp16) load ----

__device__ __forceinline__ void add6(float* a, uint4 g) {
  float2 f0 = __half22float2(*(__half2*)&g.x);
  float2 f1 = __half22float2(*(__half2*)&g.y);
  float2 f2 = __half22float2(*(__half2*)&g.z);
  a[0] += f0.x; a[1] += f0.y; a[2] += f1.x;
  a[3] += f1.y; a[4] += f2.x; a[5] += f2.y;
}

__global__ __launch_bounds__(256) void layer1_kernel(
    const __half* __restrict__ xs, const float* __restrict__ W1,
    const float* __restrict__ b1, const float* __restrict__ gam,
    const float* __restrict__ bet, const uint4* __restrict__ meta,
    const int* __restrict__ csr8,
    unsigned char* __restrict__ hout, int n) {
  int v = blockIdx.x * 4 + (threadIdx.x >> 6);
  if (v >= n) return;
  int lane = threadIdx.x & 63;
  int M8 = NCOH * n;
  const uint4* xs4 = (const uint4*)xs;  // one row = 8 halves = 16B
  uint4 mt = meta[v];                   // broadcast: 1 line for counts+dinv
  float dv = __uint_as_float(mt.z);
  int L[NCOH + 1];
  unpack_L(mt, L);
  int deg = L[NCOH];
  float a[6] = {0.f, 0.f, 0.f, 0.f, 0.f, 0.f};
  for (int c0 = 0; c0 < deg; c0 += 64) {
    int p = c0 + lane;
    if (p < deg) {
      int u = 0;
#pragma unroll
      for (int t = 1; t < NCOH; ++t) u += (p >= L[t]);
      int s = csr8[(p - L[u]) * M8 + u * n + v];  // lane-owned edge, plane-major
      add6(a, xs4[s]);
    }
  }
  if (lane == 0) add6(a, xs4[v]);  // self-loop
#pragma unroll
  for (int off = 32; off >= 1; off >>= 1) {
#pragma unroll
    for (int j = 0; j < 6; ++j) a[j] += __shfl_xor(a[j], off, 64);
  }
#pragma unroll
  for (int j = 0; j < 6; ++j) a[j] *= dv;
  int f0 = lane, f1 = lane + 64;
  float o0 = b1[f0], o1 = b1[f1];
#pragma unroll
  for (int j = 0; j < 6; ++j) {
    o0 = fmaf(a[j], W1[j * HDIM + f0], o0);
    o1 = fmaf(a[j], W1[j * HDIM + f1], o1);
  }
  float s = o0 + o1, q = o0 * o0 + o1 * o1;
#pragma unroll
  for (int off = 32; off >= 1; off >>= 1) {
    s += __shfl_xor(s, off, 64);
    q += __shfl_xor(q, off, 64);
  }
  float m = s * (1.0f / HDIM);
  float var = fmaxf(q * (1.0f / HDIM) - m * m, 0.f);
  float rs = rsqrtf(var + LN_EPS);
  float y0 = fmaxf(fmaf((o0 - m) * rs, gam[f0], bet[f0]), 0.f);
  float y1 = fmaxf(fmaf((o1 - m) * rs, gam[f1], bet[f1]), 0.f);
  // store h' = dinv*h as fp8 e4m3 (HW cvt; byte 0 of the packed pair)
  unsigned char c0 = (unsigned char)(__builtin_amdgcn_cvt_pk_fp8_f32(y0 * dv, 0.f, 0, false) & 0xff);
  unsigned char c1 = (unsigned char)(__builtin_amdgcn_cvt_pk_fp8_f32(y1 * dv, 0.f, 0, false) & 0xff);
  hout[(size_t)v * 128 + f0] = c0;
  hout[(size_t)v * 128 + f1] = c1;
}

// ---------------- Aggregation: 2 nodes/wave, 4B/lane (4x fp8), 16-deep => 32 rows in flight ----

__device__ __forceinline__ void add4f8(float& a0, float& a1, float& a2, float& a3, unsigned g) {
  f32x2 lo = __builtin_amdgcn_cvt_pk_f32_fp8(g, false);
  f32x2 hi = __builtin_amdgcn_cvt_pk_f32_fp8(g, true);
  a0 += lo.x; a1 += lo.y; a2 += hi.x; a3 += hi.y;
}

__global__ __launch_bounds__(256) void agg_kernel(
    const unsigned char* __restrict__ hin, const uint4* __restrict__ meta,
    const int* __restrict__ csr8,
    __half* __restrict__ agg, int n) {
  int lane = threadIdx.x & 63;
  int wave = threadIdx.x >> 6;
  int hl = lane & 31;                              // lane within half-wave
  int v = blockIdx.x * 8 + wave * 2 + (lane >> 5); // 2 nodes per wave
  int vc = v < n ? v : n - 1;
  int M8 = NCOH * n;
  const unsigned* h8 = (const unsigned*)hin;  // 4B units (4 fp8); row = 32 units (128B)
  unsigned self = h8[(size_t)vc * 32 + hl];
  float a0 = 0.f, a1 = 0.f, a2 = 0.f, a3 = 0.f;
  add4f8(a0, a1, a2, a3, self);  // self-loop

  uint4 mt = meta[vc];  // broadcast within half-wave: counts+dinv in one 16B load
  float dv = __uint_as_float(mt.z);
  int L[NCOH + 1];
  unpack_L(mt, L);
  int deg = L[NCOH];
  for (int c0 = 0; c0 < deg; c0 += 32) {
    int p = c0 + hl;
    int myidx = 0;
    if (p < deg) {
      int u = 0;
#pragma unroll
      for (int t = 1; t < NCOH; ++t) u += (p >= L[t]);
      myidx = csr8[(p - L[u]) * M8 + u * n + vc];  // lane-parallel index preload
    }
    int cnt = min(deg - c0, 32);
    for (int j = 0; j < cnt; j += 16) {
      unsigned g[16];
#pragma unroll
      for (int u = 0; u < 16; ++u) {
        int s = __shfl(myidx, min(j + u, cnt - 1), 32);  // clamp: loads unconditional
        g[u] = h8[(size_t)s * 32 + hl];
      }
#pragma unroll
      for (int u = 0; u < 16; ++u) {
        if (j + u < cnt) add4f8(a0, a1, a2, a3, g[u]);  // masked add
      }
    }
  }
  if (v < n) {
    uint2 outp;
    __half2 lo = __floats2half2_rn(a0 * dv, a1 * dv);
    __half2 hi = __floats2half2_rn(a2 * dv, a3 * dv);
    outp.x = *(unsigned*)&lo;
    outp.y = *(unsigned*)&hi;
    ((uint2*)agg)[(size_t)v * 32 + hl] = outp;  // aggbuf stays fp16 (GEMM A-operand)
  }
}

// ---------------- MFMA GEMM + LN (+ReLU -> fp8 h' | + MFMA head -> out) ----------------
// 64 rows / 4 waves / 35KB LDS weight stage (measured best form).

__global__ __launch_bounds__(256) void mfma_gemm_kernel(
    const __half* __restrict__ aggh, const __half* __restrict__ Wt,
    const float* __restrict__ bias, const float* __restrict__ gam,
    const float* __restrict__ bet, const float* __restrict__ dinv,
    unsigned char* __restrict__ hout,
    const __half* __restrict__ rW1t, const float* __restrict__ rb1,
    const float* __restrict__ rW2, const float* __restrict__ rb2,
    float* __restrict__ out, int n, int mode) {
  __shared__ __align__(16) __half smem[128 * 136];  // Wt staged; later aliased as tile
  int tid = threadIdx.x;
  int v0 = blockIdx.x * 64;
  int lane = tid & 63;
  int wv = tid >> 6;
  int m = lane & 15;
  int q = lane >> 4;

#pragma unroll
  for (int i = 0; i < 8; ++i) {
    int u = tid + i * 256;
    int row = u >> 4, seg = u & 15;
    *(uint4*)&smem[row * 136 + seg * 8] = *(const uint4*)&Wt[row * 128 + seg * 8];
  }

  int row = v0 + wv * 16 + m;
  int rowc = row < n ? row : n - 1;
  const __half* abase = aggh + (size_t)rowc * 128 + q * 8;
  half8 afrag[4];
#pragma unroll
  for (int kt = 0; kt < 4; ++kt) afrag[kt] = *(const half8*)(abase + kt * 32);

  __syncthreads();

  f32x4 acc[8];
#pragma unroll
  for (int c = 0; c < 8; ++c) acc[c] = (f32x4){0.f, 0.f, 0.f, 0.f};
#pragma unroll
  for (int kt = 0; kt < 4; ++kt) {
#pragma unroll
    for (int c = 0; c < 8; ++c) {
      half8 b = *(const half8*)&smem[(c * 16 + m) * 136 + kt * 32 + q * 8];
      acc[c] = __builtin_amdgcn_mfma_f32_16x16x32_f16(afrag[kt], b, acc[c], 0, 0, 0);
    }
  }

#pragma unroll
  for (int c = 0; c < 8; ++c) {
    float bcol = bias[c * 16 + m];
#pragma unroll
    for (int r = 0; r < 4; ++r) acc[c][r] += bcol;
  }
  float mean[4], rstd[4], dvr[4];
#pragma unroll
  for (int r = 0; r < 4; ++r) {
    float s = 0.f, q2 = 0.f;
#pragma unroll
    for (int c = 0; c < 8; ++c) {
      float vv = acc[c][r];
      s += vv;
      q2 += vv * vv;
    }
#pragma unroll
    for (int off = 8; off >= 1; off >>= 1) {
      s += __shfl_xor(s, off, 16);
      q2 += __shfl_xor(q2, off, 16);
    }
    float mu = s * (1.f / HDIM);
    float var = fmaxf(q2 * (1.f / HDIM) - mu * mu, 0.f);
    mean[r] = mu;
    rstd[r] = rsqrtf(var + LN_EPS);
    int vr = v0 + wv * 16 + q * 4 + r;
    dvr[r] = (mode == 1 && vr < n) ? dinv[vr] : 1.f;
  }

  __syncthreads();
  __half* tile = smem;  // 64 x 136
#pragma unroll
  for (int c = 0; c < 8; ++c) {
    float g = gam[c * 16 + m], bb = bet[c * 16 + m];
#pragma unroll
    for (int r = 0; r < 4; ++r) {
      float y = fmaf((acc[c][r] - mean[r]) * rstd[r], g, bb);
      if (mode == 1) y = fmaxf(y, 0.f) * dvr[r];
      tile[(wv * 16 + q * 4 + r) * 136 + c * 16 + m] = __float2half(y);
    }
  }
  __syncthreads();

  if (mode == 1) {
    // h' -> fp8 e4m3, 8B (8 features) per thread-iter
#pragma unroll
    for (int i = 0; i < 4; ++i) {
      int u = tid + i * 256;
      int r = u >> 4, seg = u & 15;
      int v = v0 + r;
      if (v < n) {
        half8 hv = *(const half8*)&tile[r * 136 + seg * 8];
        int w0 = __builtin_amdgcn_cvt_pk_fp8_f32((float)hv[0], (float)hv[1], 0, false);
        w0 = __builtin_amdgcn_cvt_pk_fp8_f32((float)hv[2], (float)hv[3], w0, true);
        int w1 = __builtin_amdgcn_cvt_pk_fp8_f32((float)hv[4], (float)hv[5], 0, false);
        w1 = __builtin_amdgcn_cvt_pk_fp8_f32((float)hv[6], (float)hv[7], w1, true);
        uint2 o;
        o.x = (unsigned)w0;
        o.y = (unsigned)w1;
        *(uint2*)&hout[(size_t)v * 128 + seg * 8] = o;
      }
    }
    return;
  }

  f32x4 hacc[4];
#pragma unroll
  for (int c = 0; c < 4; ++c) hacc[c] = (f32x4){0.f, 0.f, 0.f, 0.f};
#pragma unroll
  for (int kt = 0; kt < 4; ++kt) {
    half8 a = *(const half8*)&tile[(wv * 16 + m) * 136 + kt * 32 + q * 8];
#pragma unroll
    for (int c = 0; c < 4; ++c) {
      half8 b = *(const half8*)&rW1t[(c * 16 + m) * 128 + kt * 32 + q * 8];
      hacc[c] = __builtin_amdgcn_mfma_f32_16x16x32_f16(a, b, hacc[c], 0, 0, 0);
    }
  }
  float p[4] = {0.f, 0.f, 0.f, 0.f};
#pragma unroll
  for (int c = 0; c < 4; ++c) {
    float rb = rb1[c * 16 + m], w2 = rW2[c * 16 + m];
#pragma unroll
    for (int r = 0; r < 4; ++r) {
      float hv = fmaxf(hacc[c][r] + rb, 0.f);
      p[r] = fmaf(hv, w2, p[r]);
    }
  }
#pragma unroll
  for (int r = 0; r < 4; ++r) {
#pragma unroll
    for (int off = 8; off >= 1; off >>= 1) p[r] += __shfl_xor(p[r], off, 16);
  }
  if (m == 0) {
    float rb2v = rb2[0];
#pragma unroll
    for (int r = 0; r < 4; ++r) {
      int v = v0 + wv * 16 + q * 4 + r;
      if (v < n) out[v] = 1.f / (1.f + expf(-(p[r] + rb2v)));
    }
  }
}

// ---------------- Launch ----------------

extern "C" void kernel_launch(void* const* d_in, const int* in_sizes, int n_in,
                              void* d_out, int out_size, void* d_ws, size_t ws_size,
                              hipStream_t stream) {
  const float* x   = (const float*)d_in[0];
  const int*  eidx = (const int*)d_in[1];
  const float* W1  = (const float*)d_in[2];
  const float* b1  = (const float*)d_in[3];
  const float* W2  = (const float*)d_in[4];
  const float* b2  = (const float*)d_in[5];
  const float* W3  = (const float*)d_in[6];
  const float* b3  = (const float*)d_in[7];
  const float* g1  = (const float*)d_in[8];
  const float* be1 = (const float*)d_in[9];
  const float* g2  = (const float*)d_in[10];
  const float* be2 = (const float*)d_in[11];
  const float* g3  = (const float*)d_in[12];
  const float* be3 = (const float*)d_in[13];
  const float* rW1 = (const float*)d_in[14];
  const float* rb1 = (const float*)d_in[15];
  const float* rW2 = (const float*)d_in[16];
  const float* rb2 = (const float*)d_in[17];

  int N = in_sizes[0] / 6;
  int E = in_sizes[1] / 2;
  const int* srcp = eidx;
  const int* dstp = eidx + E;
  float* out = (float*)d_out;

  char* p = (char*)d_ws;
  auto alloc = [&](size_t bytes) -> void* {
    void* r = (void*)p;
    p += (bytes + 255) & ~(size_t)255;
    return r;
  };
  int*    counts8  = (int*)alloc((size_t)NCOH * N * 4);
  float*  dinvp    = (float*)alloc((size_t)N * 4);
  uint4*  meta     = (uint4*)alloc((size_t)N * 16);
  int*    csr8     = (int*)alloc((size_t)NCOH * N * CAP * 4);  // slot-major planes
  __half* xs       = (__half*)alloc((size_t)N * 8 * 2);
  unsigned char* h8_a = (unsigned char*)alloc((size_t)N * HDIM);
  unsigned char* h8_b = (unsigned char*)alloc((size_t)N * HDIM);
  __half* aggbuf   = (__half*)alloc((size_t)N * HDIM * 2);
  __half* w2t      = (__half*)alloc((size_t)HDIM * HDIM * 2);
  __half* w3t      = (__half*)alloc((size_t)HDIM * HDIM * 2);
  __half* rw1t     = (__half*)alloc((size_t)64 * HDIM * 2);

  int M8 = NCOH * N;

  hipMemsetAsync(counts8, 0, (size_t)M8 * 4, stream);
  int nEdgeThreads = (E + 1) / 2;
  build_kernel<<<(nEdgeThreads + 255) / 256, 256, 0, stream>>>(srcp, dstp, counts8, csr8, E, N);
  prep_kernel<<<(N * 8 + 40960 + 255) / 256, 256, 0, stream>>>(x, counts8, dinvp, xs, meta,
                                                               W2, W3, rW1, w2t, w3t, rw1t, N);

  int nw = (N + 3) / 4;     // layer1: one wave per node
  int nw2 = (N + 7) / 8;    // agg: two nodes per wave
  int nb = (N + 63) / 64;   // gemm: 64 rows per 4-wave block
  layer1_kernel<<<nw, 256, 0, stream>>>(xs, W1, b1, g1, be1, meta, csr8, h8_a, N);
  agg_kernel<<<nw2, 256, 0, stream>>>(h8_a, meta, csr8, aggbuf, N);
  mfma_gemm_kernel<<<nb, 256, 0, stream>>>(aggbuf, w2t, b2, g2, be2, dinvp, h8_b,
                                           rw1t, rb1, rW2, rb2, out, N, 1);
  agg_kernel<<<nw2, 256, 0, stream>>>(h8_b, meta, csr8, aggbuf, N);
  mfma_gemm_kernel<<<nb, 256, 0, stream>>>(aggbuf, w3t, b3, g3, be3, dinvp, h8_b,
                                           rw1t, rb1, rW2, rb2, out, N, 2);
}

// Round 12
// 227.359 us; speedup vs baseline: 1.0585x; 1.0585x over previous
//
#include <hip/hip_runtime.h>
#include <hip/hip_fp16.h>
#include <math.h>

#define HDIM 128
#define LN_EPS 1e-5f
#define NCOH 8   // XCD cohorts (blockIdx & 7 — build-write locality; R23's src-slice
                 // cohort regressed: deg~16 < 32-lane round => no temporal slicing,
                 // and build WRITE_SIZE 35->53MB from cross-plane scatter)
#define CAP 24   // per-(node,cohort) slot capacity; Poisson(2) => P(overflow) ~1e-12

typedef _Float16 half8 __attribute__((ext_vector_type(8)));
typedef float f32x4 __attribute__((ext_vector_type(4)));
typedef float f32x2 __attribute__((ext_vector_type(2)));

// R24 = exact revert to R18/R22 (measured 228.2/230.5us best). Full lever map:
// fused-64 (-46), fused-16 (-4), feature-split (-52), src-sliced cohorts (-10),
// wider loads (neutral) all lose; ladder of wins: single-pass CSR (+37),
// gemm 64-row LDS form + xs fp16 (+19), fp8 h' (+19), packed meta (+10).
// agg gather = ~500-stream latency-saturated random-line access over 6.4MB
// (> 4MB per-XCD L2), rounds already minimal (1-2/node), bytes already fp8.
// Floor arithmetic: 2x agg ~76 + layer1 ~30 + build ~35 + prep ~10 + 2x gemm
// ~50 + tails ~= 230us.

// ---------------- CSR build: one pass, 2 edges/thread ----------------

__global__ void build_kernel(const int* __restrict__ src, const int* __restrict__ dst,
                             int* __restrict__ counts8, int* __restrict__ csr8,
                             int E, int n) {
  int t = blockIdx.x * blockDim.x + threadIdx.x;
  int x = blockIdx.x & (NCOH - 1);
  int M8 = NCOH * n;
  int e0 = t * 2;
  if (e0 + 1 < E) {
    int2 d = *(const int2*)&dst[e0];
    int2 s = *(const int2*)&src[e0];
    int slot0 = atomicAdd(&counts8[x * n + d.x], 1);
    if (slot0 < CAP) csr8[slot0 * M8 + x * n + d.x] = s.x;
    int slot1 = atomicAdd(&counts8[x * n + d.y], 1);
    if (slot1 < CAP) csr8[slot1 * M8 + x * n + d.y] = s.y;
  } else if (e0 < E) {
    int d = dst[e0];
    int slot = atomicAdd(&counts8[x * n + d], 1);
    if (slot < CAP) csr8[slot * M8 + x * n + d] = src[e0];
  }
}

// ---------------- Prep: meta (packed counts+dinv), dinv, xs (fp16), fp16-T weights ----

__global__ void prep_kernel(const float* __restrict__ x, const int* __restrict__ counts8,
                            float* __restrict__ dinv, __half* __restrict__ xs,
                            uint4* __restrict__ meta,
                            const float* __restrict__ W2, const float* __restrict__ W3,
                            const float* __restrict__ rW1, __half* __restrict__ w2t,
                            __half* __restrict__ w3t, __half* __restrict__ rw1t, int n) {
  int idx = blockIdx.x * 256 + threadIdx.x;
  int nx = n * 8;
  if (idx < nx) {
    int vv = idx >> 3, j = idx & 7;  // 8 lanes per node (group-aligned within wave)
    int c = counts8[j * n + vv];
    int s = c;
    s += __shfl_xor(s, 1, 8);
    s += __shfl_xor(s, 2, 8);
    s += __shfl_xor(s, 4, 8);
    float dv = rsqrtf((float)(s + 1));  // +1 self-loop (raw counts incl. overflow)
    xs[idx] = __float2half((j < 6) ? x[vv * 6 + j] * dv : 0.f);
    // pack meta[vv] = {counts bytes 0..7 (clamped to CAP), dinv, 0}
    unsigned w = (unsigned)min(c, CAP) << ((j & 3) * 8);
    w |= __shfl_xor(w, 1, 8);
    w |= __shfl_xor(w, 2, 8);
    unsigned other = __shfl_xor(w, 4, 8);
    unsigned lo = (j < 4) ? w : other;
    unsigned hi = (j < 4) ? other : w;
    unsigned comp = (j == 0) ? lo : (j == 1) ? hi : (j == 2) ? __float_as_uint(dv) : 0u;
    if (j < 4) ((unsigned*)meta)[vv * 4 + j] = comp;  // coalesced 16B/group
    if (j == 7) dinv[vv] = dv;
    return;
  }
  int i = idx - nx;
  if (i < 16384) {
    int nn = i >> 7, k = i & 127;
    w2t[i] = __float2half(W2[k * 128 + nn]);
  } else if (i < 32768) {
    int j = i - 16384;
    int nn = j >> 7, k = j & 127;
    w3t[j] = __float2half(W3[k * 128 + nn]);
  } else if (i < 40960) {
    int j = i - 32768;
    int nn = j >> 7, k = j & 127;
    rw1t[j] = __float2half(rW1[k * 64 + nn]);
  }
}

__device__ __forceinline__ void unpack_L(uint4 mt, int* L) {
  L[0] = 0;
  unsigned lo = mt.x, hi = mt.y;
#pragma unroll
  for (int u = 0; u < 4; ++u) L[u + 1] = L[u] + (int)((lo >> (u * 8)) & 255u);
#pragma unroll
  for (int u = 4; u < 8; ++u) L[u + 1] = L[u] + (int)((hi >> ((u - 4) * 8)) & 255u);
}

// ---------------- Layer 1: one wave/node; lane-owned edges, 1x uint4 (fp16) load ----

__device__ __forceinline__ void add6(float* a, uint4 g) {
  float2 f0 = __half22float2(*(__half2*)&g.x);
  float2 f1 = __half22float2(*(__half2*)&g.y);
  float2 f2 = __half22float2(*(__half2*)&g.z);
  a[0] += f0.x; a[1] += f0.y; a[2] += f1.x;
  a[3] += f1.y; a[4] += f2.x; a[5] += f2.y;
}

__global__ __launch_bounds__(256) void layer1_kernel(
    const __half* __restrict__ xs, const float* __restrict__ W1,
    const float* __restrict__ b1, const float* __restrict__ gam,
    const float* __restrict__ bet, const uint4* __restrict__ meta,
    const int* __restrict__ csr8,
    unsigned char* __restrict__ hout, int n) {
  int v = blockIdx.x * 4 + (threadIdx.x >> 6);
  if (v >= n) return;
  int lane = threadIdx.x & 63;
  int M8 = NCOH * n;
  const uint4* xs4 = (const uint4*)xs;  // one row = 8 halves = 16B
  uint4 mt = meta[v];                   // broadcast: 1 line for counts+dinv
  float dv = __uint_as_float(mt.z);
  int L[NCOH + 1];
  unpack_L(mt, L);
  int deg = L[NCOH];
  float a[6] = {0.f, 0.f, 0.f, 0.f, 0.f, 0.f};
  for (int c0 = 0; c0 < deg; c0 += 64) {
    int p = c0 + lane;
    if (p < deg) {
      int u = 0;
#pragma unroll
      for (int t = 1; t < NCOH; ++t) u += (p >= L[t]);
      int s = csr8[(p - L[u]) * M8 + u * n + v];  // lane-owned edge, plane-major
      add6(a, xs4[s]);
    }
  }
  if (lane == 0) add6(a, xs4[v]);  // self-loop
#pragma unroll
  for (int off = 32; off >= 1; off >>= 1) {
#pragma unroll
    for (int j = 0; j < 6; ++j) a[j] += __shfl_xor(a[j], off, 64);
  }
#pragma unroll
  for (int j = 0; j < 6; ++j) a[j] *= dv;
  int f0 = lane, f1 = lane + 64;
  float o0 = b1[f0], o1 = b1[f1];
#pragma unroll
  for (int j = 0; j < 6; ++j) {
    o0 = fmaf(a[j], W1[j * HDIM + f0], o0);
    o1 = fmaf(a[j], W1[j * HDIM + f1], o1);
  }
  float s = o0 + o1, q = o0 * o0 + o1 * o1;
#pragma unroll
  for (int off = 32; off >= 1; off >>= 1) {
    s += __shfl_xor(s, off, 64);
    q += __shfl_xor(q, off, 64);
  }
  float m = s * (1.0f / HDIM);
  float var = fmaxf(q * (1.0f / HDIM) - m * m, 0.f);
  float rs = rsqrtf(var + LN_EPS);
  float y0 = fmaxf(fmaf((o0 - m) * rs, gam[f0], bet[f0]), 0.f);
  float y1 = fmaxf(fmaf((o1 - m) * rs, gam[f1], bet[f1]), 0.f);
  // store h' = dinv*h as fp8 e4m3 (HW cvt; byte 0 of the packed pair)
  unsigned char c0 = (unsigned char)(__builtin_amdgcn_cvt_pk_fp8_f32(y0 * dv, 0.f, 0, false) & 0xff);
  unsigned char c1 = (unsigned char)(__builtin_amdgcn_cvt_pk_fp8_f32(y1 * dv, 0.f, 0, false) & 0xff);
  hout[(size_t)v * 128 + f0] = c0;
  hout[(size_t)v * 128 + f1] = c1;
}

// ---------------- Aggregation: 2 nodes/wave, 4B/lane (4x fp8), 16-deep => 32 rows in flight ----

__device__ __forceinline__ void add4f8(float& a0, float& a1, float& a2, float& a3, unsigned g) {
  f32x2 lo = __builtin_amdgcn_cvt_pk_f32_fp8(g, false);
  f32x2 hi = __builtin_amdgcn_cvt_pk_f32_fp8(g, true);
  a0 += lo.x; a1 += lo.y; a2 += hi.x; a3 += hi.y;
}

__global__ __launch_bounds__(256) void agg_kernel(
    const unsigned char* __restrict__ hin, const uint4* __restrict__ meta,
    const int* __restrict__ csr8,
    __half* __restrict__ agg, int n) {
  int lane = threadIdx.x & 63;
  int wave = threadIdx.x >> 6;
  int hl = lane & 31;                              // lane within half-wave
  int v = blockIdx.x * 8 + wave * 2 + (lane >> 5); // 2 nodes per wave
  int vc = v < n ? v : n - 1;
  int M8 = NCOH * n;
  const unsigned* h8 = (const unsigned*)hin;  // 4B units (4 fp8); row = 32 units (128B)
  unsigned self = h8[(size_t)vc * 32 + hl];
  float a0 = 0.f, a1 = 0.f, a2 = 0.f, a3 = 0.f;
  add4f8(a0, a1, a2, a3, self);  // self-loop

  uint4 mt = meta[vc];  // broadcast within half-wave: counts+dinv in one 16B load
  float dv = __uint_as_float(mt.z);
  int L[NCOH + 1];
  unpack_L(mt, L);
  int deg = L[NCOH];
  for (int c0 = 0; c0 < deg; c0 += 32) {
    int p = c0 + hl;
    int myidx = 0;
    if (p < deg) {
      int u = 0;
#pragma unroll
      for (int t = 1; t < NCOH; ++t) u += (p >= L[t]);
      myidx = csr8[(p - L[u]) * M8 + u * n + vc];  // lane-parallel index preload
    }
    int cnt = min(deg - c0, 32);
    for (int j = 0; j < cnt; j += 16) {
      unsigned g[16];
#pragma unroll
      for (int u = 0; u < 16; ++u) {
        int s = __shfl(myidx, min(j + u, cnt - 1), 32);  // clamp: loads unconditional
        g[u] = h8[(size_t)s * 32 + hl];
      }
#pragma unroll
      for (int u = 0; u < 16; ++u) {
        if (j + u < cnt) add4f8(a0, a1, a2, a3, g[u]);  // masked add
      }
    }
  }
  if (v < n) {
    uint2 outp;
    __half2 lo = __floats2half2_rn(a0 * dv, a1 * dv);
    __half2 hi = __floats2half2_rn(a2 * dv, a3 * dv);
    outp.x = *(unsigned*)&lo;
    outp.y = *(unsigned*)&hi;
    ((uint2*)agg)[(size_t)v * 32 + hl] = outp;  // aggbuf stays fp16 (GEMM A-operand)
  }
}

// ---------------- MFMA GEMM + LN (+ReLU -> fp8 h' | + MFMA head -> out) ----------------
// 64 rows / 4 waves / 35KB LDS weight stage (measured best form).

__global__ __launch_bounds__(256) void mfma_gemm_kernel(
    const __half* __restrict__ aggh, const __half* __restrict__ Wt,
    const float* __restrict__ bias, const float* __restrict__ gam,
    const float* __restrict__ bet, const float* __restrict__ dinv,
    unsigned char* __restrict__ hout,
    const __half* __restrict__ rW1t, const float* __restrict__ rb1,
    const float* __restrict__ rW2, const float* __restrict__ rb2,
    float* __restrict__ out, int n, int mode) {
  __shared__ __align__(16) __half smem[128 * 136];  // Wt staged; later aliased as tile
  int tid = threadIdx.x;
  int v0 = blockIdx.x * 64;
  int lane = tid & 63;
  int wv = tid >> 6;
  int m = lane & 15;
  int q = lane >> 4;

#pragma unroll
  for (int i = 0; i < 8; ++i) {
    int u = tid + i * 256;
    int row = u >> 4, seg = u & 15;
    *(uint4*)&smem[row * 136 + seg * 8] = *(const uint4*)&Wt[row * 128 + seg * 8];
  }

  int row = v0 + wv * 16 + m;
  int rowc = row < n ? row : n - 1;
  const __half* abase = aggh + (size_t)rowc * 128 + q * 8;
  half8 afrag[4];
#pragma unroll
  for (int kt = 0; kt < 4; ++kt) afrag[kt] = *(const half8*)(abase + kt * 32);

  __syncthreads();

  f32x4 acc[8];
#pragma unroll
  for (int c = 0; c < 8; ++c) acc[c] = (f32x4){0.f, 0.f, 0.f, 0.f};
#pragma unroll
  for (int kt = 0; kt < 4; ++kt) {
#pragma unroll
    for (int c = 0; c < 8; ++c) {
      half8 b = *(const half8*)&smem[(c * 16 + m) * 136 + kt * 32 + q * 8];
      acc[c] = __builtin_amdgcn_mfma_f32_16x16x32_f16(afrag[kt], b, acc[c], 0, 0, 0);
    }
  }

#pragma unroll
  for (int c = 0; c < 8; ++c) {
    float bcol = bias[c * 16 + m];
#pragma unroll
    for (int r = 0; r < 4; ++r) acc[c][r] += bcol;
  }
  float mean[4], rstd[4], dvr[4];
#pragma unroll
  for (int r = 0; r < 4; ++r) {
    float s = 0.f, q2 = 0.f;
#pragma unroll
    for (int c = 0; c < 8; ++c) {
      float vv = acc[c][r];
      s += vv;
      q2 += vv * vv;
    }
#pragma unroll
    for (int off = 8; off >= 1; off >>= 1) {
      s += __shfl_xor(s, off, 16);
      q2 += __shfl_xor(q2, off, 16);
    }
    float mu = s * (1.f / HDIM);
    float var = fmaxf(q2 * (1.f / HDIM) - mu * mu, 0.f);
    mean[r] = mu;
    rstd[r] = rsqrtf(var + LN_EPS);
    int vr = v0 + wv * 16 + q * 4 + r;
    dvr[r] = (mode == 1 && vr < n) ? dinv[vr] : 1.f;
  }

  __syncthreads();
  __half* tile = smem;  // 64 x 136
#pragma unroll
  for (int c = 0; c < 8; ++c) {
    float g = gam[c * 16 + m], bb = bet[c * 16 + m];
#pragma unroll
    for (int r = 0; r < 4; ++r) {
      float y = fmaf((acc[c][r] - mean[r]) * rstd[r], g, bb);
      if (mode == 1) y = fmaxf(y, 0.f) * dvr[r];
      tile[(wv * 16 + q * 4 + r) * 136 + c * 16 + m] = __float2half(y);
    }
  }
  __syncthreads();

  if (mode == 1) {
    // h' -> fp8 e4m3, 8B (8 features) per thread-iter
#pragma unroll
    for (int i = 0; i < 4; ++i) {
      int u = tid + i * 256;
      int r = u >> 4, seg = u & 15;
      int v = v0 + r;
      if (v < n) {
        half8 hv = *(const half8*)&tile[r * 136 + seg * 8];
        int w0 = __builtin_amdgcn_cvt_pk_fp8_f32((float)hv[0], (float)hv[1], 0, false);
        w0 = __builtin_amdgcn_cvt_pk_fp8_f32((float)hv[2], (float)hv[3], w0, true);
        int w1 = __builtin_amdgcn_cvt_pk_fp8_f32((float)hv[4], (float)hv[5], 0, false);
        w1 = __builtin_amdgcn_cvt_pk_fp8_f32((float)hv[6], (float)hv[7], w1, true);
        uint2 o;
        o.x = (unsigned)w0;
        o.y = (unsigned)w1;
        *(uint2*)&hout[(size_t)v * 128 + seg * 8] = o;
      }
    }
    return;
  }

  f32x4 hacc[4];
#pragma unroll
  for (int c = 0; c < 4; ++c) hacc[c] = (f32x4){0.f, 0.f, 0.f, 0.f};
#pragma unroll
  for (int kt = 0; kt < 4; ++kt) {
    half8 a = *(const half8*)&tile[(wv * 16 + m) * 136 + kt * 32 + q * 8];
#pragma unroll
    for (int c = 0; c < 4; ++c) {
      half8 b = *(const half8*)&rW1t[(c * 16 + m) * 128 + kt * 32 + q * 8];
      hacc[c] = __builtin_amdgcn_mfma_f32_16x16x32_f16(a, b, hacc[c], 0, 0, 0);
    }
  }
  float p[4] = {0.f, 0.f, 0.f, 0.f};
#pragma unroll
  for (int c = 0; c < 4; ++c) {
    float rb = rb1[c * 16 + m], w2 = rW2[c * 16 + m];
#pragma unroll
    for (int r = 0; r < 4; ++r) {
      float hv = fmaxf(hacc[c][r] + rb, 0.f);
      p[r] = fmaf(hv, w2, p[r]);
    }
  }
#pragma unroll
  for (int r = 0; r < 4; ++r) {
#pragma unroll
    for (int off = 8; off >= 1; off >>= 1) p[r] += __shfl_xor(p[r], off, 16);
  }
  if (m == 0) {
    float rb2v = rb2[0];
#pragma unroll
    for (int r = 0; r < 4; ++r) {
      int v = v0 + wv * 16 + q * 4 + r;
      if (v < n) out[v] = 1.f / (1.f + expf(-(p[r] + rb2v)));
    }
  }
}

// ---------------- Launch ----------------

extern "C" void kernel_launch(void* const* d_in, const int* in_sizes, int n_in,
                              void* d_out, int out_size, void* d_ws, size_t ws_size,
                              hipStream_t stream) {
  const float* x   = (const float*)d_in[0];
  const int*  eidx = (const int*)d_in[1];
  const float* W1  = (const float*)d_in[2];
  const float* b1  = (const float*)d_in[3];
  const float* W2  = (const float*)d_in[4];
  const float* b2  = (const float*)d_in[5];
  const float* W3  = (const float*)d_in[6];
  const float* b3  = (const float*)d_in[7];
  const float* g1  = (const float*)d_in[8];
  const float* be1 = (const float*)d_in[9];
  const float* g2  = (const float*)d_in[10];
  const float* be2 = (const float*)d_in[11];
  const float* g3  = (const float*)d_in[12];
  const float* be3 = (const float*)d_in[13];
  const float* rW1 = (const float*)d_in[14];
  const float* rb1 = (const float*)d_in[15];
  const float* rW2 = (const float*)d_in[16];
  const float* rb2 = (const float*)d_in[17];

  int N = in_sizes[0] / 6;
  int E = in_sizes[1] / 2;
  const int* srcp = eidx;
  const int* dstp = eidx + E;
  float* out = (float*)d_out;

  char* p = (char*)d_ws;
  auto alloc = [&](size_t bytes) -> void* {
    void* r = (void*)p;
    p += (bytes + 255) & ~(size_t)255;
    return r;
  };
  int*    counts8  = (int*)alloc((size_t)NCOH * N * 4);
  float*  dinvp    = (float*)alloc((size_t)N * 4);
  uint4*  meta     = (uint4*)alloc((size_t)N * 16);
  int*    csr8     = (int*)alloc((size_t)NCOH * N * CAP * 4);  // slot-major planes
  __half* xs       = (__half*)alloc((size_t)N * 8 * 2);
  unsigned char* h8_a = (unsigned char*)alloc((size_t)N * HDIM);
  unsigned char* h8_b = (unsigned char*)alloc((size_t)N * HDIM);
  __half* aggbuf   = (__half*)alloc((size_t)N * HDIM * 2);
  __half* w2t      = (__half*)alloc((size_t)HDIM * HDIM * 2);
  __half* w3t      = (__half*)alloc((size_t)HDIM * HDIM * 2);
  __half* rw1t     = (__half*)alloc((size_t)64 * HDIM * 2);

  int M8 = NCOH * N;

  hipMemsetAsync(counts8, 0, (size_t)M8 * 4, stream);
  int nEdgeThreads = (E + 1) / 2;
  build_kernel<<<(nEdgeThreads + 255) / 256, 256, 0, stream>>>(srcp, dstp, counts8, csr8, E, N);
  prep_kernel<<<(N * 8 + 40960 + 255) / 256, 256, 0, stream>>>(x, counts8, dinvp, xs, meta,
                                                               W2, W3, rW1, w2t, w3t, rw1t, N);

  int nw = (N + 3) / 4;     // layer1: one wave per node
  int nw2 = (N + 7) / 8;    // agg: two nodes per wave
  int nb = (N + 63) / 64;   // gemm: 64 rows per 4-wave block
  layer1_kernel<<<nw, 256, 0, stream>>>(xs, W1, b1, g1, be1, meta, csr8, h8_a, N);
  agg_kernel<<<nw2, 256, 0, stream>>>(h8_a, meta, csr8, aggbuf, N);
  mfma_gemm_kernel<<<nb, 256, 0, stream>>>(aggbuf, w2t, b2, g2, be2, dinvp, h8_b,
                                           rw1t, rb1, rW2, rb2, out, N, 1);
  agg_kernel<<<nw2, 256, 0, stream>>>(h8_b, meta, csr8, aggbuf, N);
  mfma_gemm_kernel<<<nb, 256, 0, stream>>>(aggbuf, w3t, b3, g3, be3, dinvp, h8_b,
                                           rw1t, rb1, rW2, rb2, out, N, 2);
}